// Round 1
// baseline (230.743 us; speedup 1.0000x reference)
//
#include <hip/hip_runtime.h>

#define DIM 512
#define HID 2048
#define NEXP 8

typedef __attribute__((ext_vector_type(8))) short v8s;   // 8 x bf16 (as bits) = 4 VGPR
typedef __attribute__((ext_vector_type(4))) float v4f;   // MFMA accumulator

__device__ __forceinline__ unsigned short f2bf(float f) {
  union { __bf16 b; unsigned short u; } c;
  c.b = (__bf16)f;   // RTNE; compiler fuses pairs into v_cvt_pk_bf16_f32 (m240)
  return c.u;
}

// ---------------- routing prep ----------------
__global__ void route_prep(const int* __restrict__ route, int* __restrict__ meta, int ntok) {
  __shared__ int c[NEXP];
  int t = threadIdx.x;
  if (t < NEXP) c[t] = 0;
  __syncthreads();
  for (int n = t; n < ntok; n += blockDim.x) atomicAdd(&c[route[n]], 1);
  __syncthreads();
  if (t == 0) {
    int acc = 0;
    for (int e = 0; e < NEXP; ++e) {
      meta[e] = c[e];            // count
      meta[NEXP + e] = acc;      // offset
      meta[2 * NEXP + e] = acc;  // cursor (consumed by fill_perm)
      acc += c[e];
    }
  }
}

__global__ void fill_perm(const int* __restrict__ route, int* __restrict__ meta,
                          int* __restrict__ perm, int ntok) {
  int n = blockIdx.x * blockDim.x + threadIdx.x;
  if (n < ntok) {
    int p = atomicAdd(&meta[2 * NEXP + route[n]], 1);
    perm[p] = n;
  }
}

// ---------------- GEMM1: h = silu(x@wg + bg) * (x@wi + bi), bf16 out ----------------
// BM=128, BN=128, BK=64, 256 thr (4 waves 2x2, 64x64 per wave).
// LDS tiles [row][k] with 144B row stride (9*16B: bank-walking, b128-aligned).
__global__ __launch_bounds__(256, 2) void gemm1(
    const float* __restrict__ x,
    const float* __restrict__ wg_, const float* __restrict__ bg_,
    const float* __restrict__ wi_, const float* __restrict__ bi_,
    const int* __restrict__ meta, const int* __restrict__ perm,
    unsigned short* __restrict__ hbuf)
{
  constexpr int BM = 128, BN = 128, ROWB = 144;
  const int e = blockIdx.z;
  const int cnt = meta[e];
  const int m0 = blockIdx.y * BM;
  if (m0 >= cnt) return;
  const int off = meta[NEXP + e];
  const int n0 = blockIdx.x * BN;

  __shared__ __align__(16) unsigned char sA[BM * ROWB];
  __shared__ __align__(16) unsigned char sG[BN * ROWB];
  __shared__ __align__(16) unsigned char sI[BN * ROWB];

  const int t = threadIdx.x;
  const int l = t & 63;
  const int w = t >> 6;
  const int wm = w >> 1, wn = w & 1;
  const int fr = l & 15, fg = l >> 4;

  // A staging: 2 threads per row, 32 floats each
  const int ar = t >> 1, ah = t & 1;
  const float* asrc = nullptr;
  if (m0 + ar < cnt) asrc = x + (size_t)perm[off + m0 + ar] * DIM + ah * 32;

  // B staging lane split (bank-spread quad writes)
  const int bl = l & 7, bk = l >> 3;
  const float* wg = wg_ + (size_t)e * DIM * HID;
  const float* wi = wi_ + (size_t)e * DIM * HID;

  v4f accG[4][4], accI[4][4];
  #pragma unroll
  for (int i = 0; i < 4; ++i)
    #pragma unroll
    for (int j = 0; j < 4; ++j) {
      accG[i][j] = (v4f){0.f, 0.f, 0.f, 0.f};
      accI[i][j] = (v4f){0.f, 0.f, 0.f, 0.f};
    }

  for (int k0 = 0; k0 < DIM; k0 += 64) {
    // ---- stage A (f32 -> bf16) ----
    {
      float f[32];
      if (asrc) {
        const float4* p = (const float4*)(asrc + k0);
        #pragma unroll
        for (int j = 0; j < 8; ++j) {
          float4 q = p[j];
          f[4*j] = q.x; f[4*j+1] = q.y; f[4*j+2] = q.z; f[4*j+3] = q.w;
        }
      } else {
        #pragma unroll
        for (int j = 0; j < 32; ++j) f[j] = 0.f;
      }
      #pragma unroll
      for (int j = 0; j < 4; ++j) {
        v8s r;
        #pragma unroll
        for (int i = 0; i < 8; ++i) r[i] = (short)f2bf(f[8*j + i]);
        *(v8s*)(sA + ar * ROWB + ah * 64 + j * 16) = r;
      }
    }
    // ---- stage B: transpose [k][n] -> LDS [n][k], gate + in ----
    #pragma unroll
    for (int p = 0; p < 8; ++p) {
      const int n  = bl + 8 * (w + 4 * (p & 3));   // [0,128)
      const int kq = bk + 8 * (p >> 2);            // [0,16), k = kq*4
      const size_t go = (size_t)(k0 + kq * 4) * HID + n0 + n;
      {
        const float* s = wg + go;
        unsigned lo = f2bf(s[0])       | ((unsigned)f2bf(s[HID])   << 16);
        unsigned hi = f2bf(s[2 * HID]) | ((unsigned)f2bf(s[3*HID]) << 16);
        *(uint2*)(sG + n * ROWB + kq * 8) = make_uint2(lo, hi);
      }
      {
        const float* s = wi + go;
        unsigned lo = f2bf(s[0])       | ((unsigned)f2bf(s[HID])   << 16);
        unsigned hi = f2bf(s[2 * HID]) | ((unsigned)f2bf(s[3*HID]) << 16);
        *(uint2*)(sI + n * ROWB + kq * 8) = make_uint2(lo, hi);
      }
    }
    __syncthreads();
    #pragma unroll
    for (int kk = 0; kk < 2; ++kk) {
      v8s af[4], gf[4], inf[4];
      #pragma unroll
      for (int mf = 0; mf < 4; ++mf)
        af[mf] = *(const v8s*)(sA + (wm*64 + mf*16 + fr) * ROWB + kk*64 + fg*16);
      #pragma unroll
      for (int nf = 0; nf < 4; ++nf) {
        gf[nf]  = *(const v8s*)(sG + (wn*64 + nf*16 + fr) * ROWB + kk*64 + fg*16);
        inf[nf] = *(const v8s*)(sI + (wn*64 + nf*16 + fr) * ROWB + kk*64 + fg*16);
      }
      #pragma unroll
      for (int mf = 0; mf < 4; ++mf)
        #pragma unroll
        for (int nf = 0; nf < 4; ++nf) {
          accG[mf][nf] = __builtin_amdgcn_mfma_f32_16x16x32_bf16(af[mf], gf[nf],  accG[mf][nf], 0, 0, 0);
          accI[mf][nf] = __builtin_amdgcn_mfma_f32_16x16x32_bf16(af[mf], inf[nf], accI[mf][nf], 0, 0, 0);
        }
    }
    __syncthreads();
  }

  // epilogue: bias + SiLU(gate)*in, write bf16 h
  #pragma unroll
  for (int nf = 0; nf < 4; ++nf) {
    const int c = n0 + wn*64 + nf*16 + fr;
    const float bg = bg_[(size_t)e * HID + c];
    const float bi = bi_[(size_t)e * HID + c];
    #pragma unroll
    for (int mf = 0; mf < 4; ++mf)
      #pragma unroll
      for (int j = 0; j < 4; ++j) {
        const int r = m0 + wm*64 + mf*16 + fg*4 + j;
        if (r < cnt) {
          const float g = accG[mf][nf][j] + bg;
          const float v = accI[mf][nf][j] + bi;
          const float hval = g / (1.f + __expf(-g)) * v;
          hbuf[(size_t)(off + r) * HID + c] = f2bf(hval);
        }
      }
  }
}

// ---------------- GEMM2: out[perm] = h @ w_out + b_out ----------------
// BM=64, BN=64, BK=64, 256 thr (4 waves 2x2, 32x32 per wave) for parallelism.
__global__ __launch_bounds__(256, 4) void gemm2(
    const unsigned short* __restrict__ hbuf,
    const float* __restrict__ wo_, const float* __restrict__ bo_,
    const int* __restrict__ meta, const int* __restrict__ perm,
    float* __restrict__ out)
{
  constexpr int BM = 64, BN = 64, ROWB = 144;
  const int e = blockIdx.z;
  const int cnt = meta[e];
  const int m0 = blockIdx.y * BM;
  if (m0 >= cnt) return;
  const int off = meta[NEXP + e];
  const int n0 = blockIdx.x * BN;

  __shared__ __align__(16) unsigned char sA[BM * ROWB];
  __shared__ __align__(16) unsigned char sB[BN * ROWB];

  const int t = threadIdx.x;
  const int l = t & 63;
  const int w = t >> 6;
  const int wm = w >> 1, wn = w & 1;
  const int fr = l & 15, fg = l >> 4;

  // A staging: 4 threads per row, 16 bf16 (32B) each
  const int ar = t >> 2, aq = t & 3;
  const unsigned short* asrc = nullptr;
  if (m0 + ar < cnt) asrc = hbuf + (size_t)(off + m0 + ar) * HID + aq * 16;

  const int bl = l & 7, bk = l >> 3;
  const float* wo = wo_ + (size_t)e * HID * DIM;

  v4f acc[2][2];
  #pragma unroll
  for (int i = 0; i < 2; ++i)
    #pragma unroll
    for (int j = 0; j < 2; ++j) acc[i][j] = (v4f){0.f, 0.f, 0.f, 0.f};

  for (int k0 = 0; k0 < HID; k0 += 64) {
    {
      uint4 u0 = make_uint4(0,0,0,0), u1 = make_uint4(0,0,0,0);
      if (asrc) {
        const uint4* p = (const uint4*)(asrc + k0);
        u0 = p[0]; u1 = p[1];
      }
      *(uint4*)(sA + ar * ROWB + aq * 32)      = u0;
      *(uint4*)(sA + ar * ROWB + aq * 32 + 16) = u1;
    }
    #pragma unroll
    for (int p = 0; p < 4; ++p) {
      const int n  = bl + 8 * (w + 4 * (p & 1));   // [0,64)
      const int kq = bk + 8 * (p >> 1);            // [0,16)
      const float* s = wo + (size_t)(k0 + kq * 4) * DIM + n0 + n;
      unsigned lo = f2bf(s[0])       | ((unsigned)f2bf(s[DIM])   << 16);
      unsigned hi = f2bf(s[2 * DIM]) | ((unsigned)f2bf(s[3*DIM]) << 16);
      *(uint2*)(sB + n * ROWB + kq * 8) = make_uint2(lo, hi);
    }
    __syncthreads();
    #pragma unroll
    for (int kk = 0; kk < 2; ++kk) {
      v8s af[2], bfr[2];
      #pragma unroll
      for (int mf = 0; mf < 2; ++mf)
        af[mf]  = *(const v8s*)(sA + (wm*32 + mf*16 + fr) * ROWB + kk*64 + fg*16);
      #pragma unroll
      for (int nf = 0; nf < 2; ++nf)
        bfr[nf] = *(const v8s*)(sB + (wn*32 + nf*16 + fr) * ROWB + kk*64 + fg*16);
      #pragma unroll
      for (int mf = 0; mf < 2; ++mf)
        #pragma unroll
        for (int nf = 0; nf < 2; ++nf)
          acc[mf][nf] = __builtin_amdgcn_mfma_f32_16x16x32_bf16(af[mf], bfr[nf], acc[mf][nf], 0, 0, 0);
    }
    __syncthreads();
  }

  #pragma unroll
  for (int nf = 0; nf < 2; ++nf) {
    const int c = n0 + wn*32 + nf*16 + fr;
    const float bo = bo_[(size_t)e * DIM + c];
    #pragma unroll
    for (int mf = 0; mf < 2; ++mf)
      #pragma unroll
      for (int j = 0; j < 4; ++j) {
        const int r = m0 + wm*32 + mf*16 + fg*4 + j;
        if (r < cnt)
          out[(size_t)perm[off + r] * DIM + c] = acc[mf][nf][j] + bo;
      }
  }
}

// ---------------- launch ----------------
extern "C" void kernel_launch(void* const* d_in, const int* in_sizes, int n_in,
                              void* d_out, int out_size, void* d_ws, size_t ws_size,
                              hipStream_t stream) {
  const float* x      = (const float*)d_in[0];
  const int*   route  = (const int*)d_in[1];
  const float* w_in   = (const float*)d_in[2];
  const float* b_in   = (const float*)d_in[3];
  const float* w_gate = (const float*)d_in[4];
  const float* b_gate = (const float*)d_in[5];
  const float* w_out  = (const float*)d_in[6];
  const float* b_out  = (const float*)d_in[7];
  float* out = (float*)d_out;

  const int ntok = in_sizes[1];  // 4096

  // ws layout: meta (24 ints) @0, perm (ntok ints) @128, h bf16 @32768
  // total = 32768 + ntok*HID*2 ≈ 16.8 MB
  int* meta = (int*)d_ws;
  int* perm = (int*)((char*)d_ws + 128);
  unsigned short* hbuf = (unsigned short*)((char*)d_ws + 32768);

  route_prep<<<1, 256, 0, stream>>>(route, meta, ntok);
  fill_perm<<<(ntok + 255) / 256, 256, 0, stream>>>(route, meta, perm, ntok);
  gemm1<<<dim3(HID / 128, (ntok + 127) / 128, NEXP), 256, 0, stream>>>(
      x, w_gate, b_gate, w_in, b_in, meta, perm, hbuf);
  gemm2<<<dim3(DIM / 64, (ntok + 63) / 64, NEXP), 256, 0, stream>>>(
      hbuf, w_out, b_out, meta, perm, out);
}

// Round 2
// 156.630 us; speedup vs baseline: 1.4732x; 1.4732x over previous
//
#include <hip/hip_runtime.h>

#define DIM 512
#define HID 2048
#define NEXP 8

typedef __attribute__((ext_vector_type(8))) short v8s;   // 8 x bf16 bits
typedef __attribute__((ext_vector_type(4))) float v4f;   // MFMA accumulator

__device__ __forceinline__ unsigned short f2bf(float f) {
  union { __bf16 b; unsigned short u; } c;
  c.b = (__bf16)f;
  return c.u;
}

__device__ __forceinline__ void gload16(const void* g, void* l) {
  __builtin_amdgcn_global_load_lds(
      (const __attribute__((address_space(1))) unsigned int*)g,
      (__attribute__((address_space(3))) unsigned int*)l, 16, 0, 0);
}

// ---------------- routing prep ----------------
__global__ void route_prep(const int* __restrict__ route, int* __restrict__ meta, int ntok) {
  __shared__ int c[NEXP];
  int t = threadIdx.x;
  if (t < NEXP) c[t] = 0;
  __syncthreads();
  for (int n = t; n < ntok; n += blockDim.x) atomicAdd(&c[route[n]], 1);
  __syncthreads();
  if (t == 0) {
    int acc = 0, pacc = 0;
    for (int e = 0; e < NEXP; ++e) {
      meta[e] = c[e];            // count
      meta[NEXP + e] = acc;      // exact offset
      meta[2 * NEXP + e] = acc;  // cursor for fill_perm
      meta[3 * NEXP + e] = pacc; // 128-padded offset (row tiles for hbuf panels)
      acc += c[e];
      pacc += ((c[e] + 127) >> 7) << 7;
    }
  }
}

__global__ void fill_perm(const int* __restrict__ route, int* __restrict__ meta,
                          int* __restrict__ perm, int ntok) {
  int n = blockIdx.x * blockDim.x + threadIdx.x;
  if (n < ntok) {
    int p = atomicAdd(&meta[2 * NEXP + route[n]], 1);
    perm[p] = n;
  }
}

// ---------------- weight conversion to bf16 panels ----------------
// Panel layout (per K-step tile of BK=64): [kq 0..7][n 0..R-1][8 k] bf16,
// i.e. element (n, k) at ushort offset ((k>>3)*R + n)*8 + (k&7).
// Fragment read = contiguous 16B per lane, conflict-free; global_load_lds-ready.

// wg/wi: R=128, per matrix: panels [e][j 0..15][s 0..7], 8192 ushorts each.
__global__ __launch_bounds__(256) void wgi_conv(
    const float* __restrict__ wg, const float* __restrict__ wi,
    unsigned short* __restrict__ wgp, unsigned short* __restrict__ wip)
{
  const int s = blockIdx.x;            // K-step (8)
  const int j = blockIdx.y;            // n-stripe (16)
  const int e = blockIdx.z >> 1;
  const int which = blockIdx.z & 1;
  const float* src = (which ? wi : wg) + (size_t)e * DIM * HID;
  unsigned short* dst = (which ? wip : wgp) + (((size_t)e * 16 + j) * 8 + s) * 8192;
  const int t = threadIdx.x;
  #pragma unroll
  for (int i = 0; i < 4; ++i) {
    const int c = t + 256 * i;         // chunk in [0,1024)
    const int kq = c >> 7, n = c & 127;
    const float* srow = src + (size_t)(s * 64 + kq * 8) * HID + j * 128 + n;
    v8s r;
    #pragma unroll
    for (int q = 0; q < 8; ++q) r[q] = (short)f2bf(srow[(size_t)q * HID]);
    *(v8s*)(dst + (size_t)c * 8) = r;
  }
}

// w_out: R=64, panels [e][j 0..7][s 0..31], 4096 ushorts each.
__global__ __launch_bounds__(256) void wo_conv(
    const float* __restrict__ wo, unsigned short* __restrict__ wop)
{
  const int s = blockIdx.x;            // K-step (32)
  const int j = blockIdx.y;            // n-stripe (8)
  const int e = blockIdx.z;
  const float* src = wo + (size_t)e * HID * DIM;
  unsigned short* dst = wop + (((size_t)e * 8 + j) * 32 + s) * 4096;
  const int t = threadIdx.x;
  #pragma unroll
  for (int i = 0; i < 2; ++i) {
    const int c = t + 256 * i;         // chunk in [0,512)
    const int kq = c >> 6, n = c & 63;
    const float* srow = src + (size_t)(s * 64 + kq * 8) * DIM + j * 64 + n;
    v8s r;
    #pragma unroll
    for (int q = 0; q < 8; ++q) r[q] = (short)f2bf(srow[(size_t)q * DIM]);
    *(v8s*)(dst + (size_t)c * 8) = r;
  }
}

// ---------------- GEMM1: h = silu(x@wg+bg)*(x@wi+bi) -> hbuf panels ----------------
// BM=128, BN=128, BK=64, 256 thr (4 waves 2x2, 64x64/wave).
// hbuf panel layout per 64-row tile: [rt][s 0..31][kq 0..7][m 0..63][8k] bf16.
__global__ __launch_bounds__(256, 2) void gemm1(
    const float* __restrict__ x,
    const unsigned short* __restrict__ wgp, const float* __restrict__ bg_,
    const unsigned short* __restrict__ wip, const float* __restrict__ bi_,
    const int* __restrict__ meta, const int* __restrict__ perm,
    unsigned short* __restrict__ hbuf)
{
  const int e = blockIdx.z;
  const int cnt = meta[e];
  const int m0 = blockIdx.y * 128;
  if (m0 >= cnt) return;
  const int off  = meta[NEXP + e];
  const int poff = meta[3 * NEXP + e];
  const int j = blockIdx.x;
  const int n0 = j * 128;

  __shared__ __align__(16) unsigned char sA[16384];
  __shared__ __align__(16) unsigned char sG[16384];
  __shared__ __align__(16) unsigned char sI[16384];

  const int t = threadIdx.x;
  const int l = t & 63, w = t >> 6;
  const int wm = w >> 1, wn = w & 1;
  const int fr = l & 15, fg = l >> 4;

  const int ar = t >> 1, ah = t & 1;   // A staging: 2 thr/row, 32 floats each
  const float* asrc = nullptr;
  if (m0 + ar < cnt) asrc = x + (size_t)perm[off + m0 + ar] * DIM + ah * 32;

  const unsigned short* pg = wgp + (((size_t)e * 16 + j) * 8) * 8192;
  const unsigned short* pi = wip + (((size_t)e * 16 + j) * 8) * 8192;

  v4f accG[4][4], accI[4][4];
  #pragma unroll
  for (int i = 0; i < 4; ++i)
    #pragma unroll
    for (int q = 0; q < 4; ++q) {
      accG[i][q] = (v4f){0.f, 0.f, 0.f, 0.f};
      accI[i][q] = (v4f){0.f, 0.f, 0.f, 0.f};
    }

  for (int s = 0; s < 8; ++s) {
    // issue weight-panel DMA first (latency hides under A cvt)
    const unsigned short* pgs = pg + s * 8192;
    const unsigned short* pis = pi + s * 8192;
    #pragma unroll
    for (int i = 0; i < 4; ++i) {
      gload16(pgs + i * 2048 + t * 8, sG + i * 4096 + w * 1024);
      gload16(pis + i * 2048 + t * 8, sI + i * 4096 + w * 1024);
    }
    // A stage: f32 -> bf16, layout [kq][m][8k]
    {
      float f[32];
      if (asrc) {
        const float4* p = (const float4*)(asrc + s * 64);
        #pragma unroll
        for (int q = 0; q < 8; ++q) {
          float4 v = p[q];
          f[4*q] = v.x; f[4*q+1] = v.y; f[4*q+2] = v.z; f[4*q+3] = v.w;
        }
      } else {
        #pragma unroll
        for (int q = 0; q < 32; ++q) f[q] = 0.f;
      }
      #pragma unroll
      for (int jj = 0; jj < 4; ++jj) {
        v8s r;
        #pragma unroll
        for (int q = 0; q < 8; ++q) r[q] = (short)f2bf(f[8*jj + q]);
        *(v8s*)(sA + ((ah * 4 + jj) * 128 + ar) * 16) = r;
      }
    }
    __syncthreads();
    #pragma unroll
    for (int kk = 0; kk < 2; ++kk) {
      v8s af[4], gf[4], inf[4];
      #pragma unroll
      for (int mf = 0; mf < 4; ++mf)
        af[mf] = *(const v8s*)(sA + ((kk*4 + fg) * 128 + wm*64 + mf*16 + fr) * 16);
      #pragma unroll
      for (int nf = 0; nf < 4; ++nf) {
        gf[nf]  = *(const v8s*)(sG + ((kk*4 + fg) * 128 + wn*64 + nf*16 + fr) * 16);
        inf[nf] = *(const v8s*)(sI + ((kk*4 + fg) * 128 + wn*64 + nf*16 + fr) * 16);
      }
      #pragma unroll
      for (int mf = 0; mf < 4; ++mf)
        #pragma unroll
        for (int nf = 0; nf < 4; ++nf) {
          accG[mf][nf] = __builtin_amdgcn_mfma_f32_16x16x32_bf16(af[mf], gf[nf],  accG[mf][nf], 0, 0, 0);
          accI[mf][nf] = __builtin_amdgcn_mfma_f32_16x16x32_bf16(af[mf], inf[nf], accI[mf][nf], 0, 0, 0);
        }
    }
    __syncthreads();
  }

  // epilogue: bias + SiLU(gate)*in -> hbuf panels (bf16)
  #pragma unroll
  for (int nf = 0; nf < 4; ++nf) {
    const int c = n0 + wn*64 + nf*16 + fr;          // k-dim of gemm2
    const float bg = bg_[(size_t)e * HID + c];
    const float bi = bi_[(size_t)e * HID + c];
    const int s_ = c >> 6, kq = (c >> 3) & 7, cb = c & 7;
    #pragma unroll
    for (int mf = 0; mf < 4; ++mf)
      #pragma unroll
      for (int jj = 0; jj < 4; ++jj) {
        const int r = wm*64 + mf*16 + fg*4 + jj;    // local row
        if (m0 + r < cnt) {
          const float g = accG[mf][nf][jj] + bg;
          const float v = accI[mf][nf][jj] + bi;
          const float hval = g / (1.f + __expf(-g)) * v;
          const int grow = poff + m0 + r;           // padded global row
          hbuf[(size_t)(grow >> 6) * 131072 + s_ * 4096 + kq * 512 + (grow & 63) * 8 + cb] = f2bf(hval);
        }
      }
  }
}

// ---------------- GEMM2: out[perm] = h @ w_out + b_out ----------------
// BM=64, BN=64, BK=64, 256 thr (4 waves 2x2, 32x32/wave). Both operands via global_load_lds.
__global__ __launch_bounds__(256, 4) void gemm2(
    const unsigned short* __restrict__ hbuf,
    const unsigned short* __restrict__ wop, const float* __restrict__ bo_,
    const int* __restrict__ meta, const int* __restrict__ perm,
    float* __restrict__ out)
{
  const int e = blockIdx.z;
  const int cnt = meta[e];
  const int m0 = blockIdx.y * 64;
  if (m0 >= cnt) return;
  const int off  = meta[NEXP + e];
  const int poff = meta[3 * NEXP + e];
  const int jn = blockIdx.x;
  const int n0 = jn * 64;

  __shared__ __align__(16) unsigned char sA[8192];
  __shared__ __align__(16) unsigned char sB[8192];

  const int t = threadIdx.x;
  const int l = t & 63, w = t >> 6;
  const int wm = w >> 1, wn = w & 1;
  const int fr = l & 15, fg = l >> 4;

  const unsigned short* pa = hbuf + (size_t)((poff + m0) >> 6) * 131072;
  const unsigned short* pb = wop + (((size_t)e * 8 + jn) * 32) * 4096;

  v4f acc[2][2];
  #pragma unroll
  for (int i = 0; i < 2; ++i)
    #pragma unroll
    for (int q = 0; q < 2; ++q) acc[i][q] = (v4f){0.f, 0.f, 0.f, 0.f};

  for (int s = 0; s < 32; ++s) {
    const unsigned short* pas = pa + s * 4096;
    const unsigned short* pbs = pb + s * 4096;
    #pragma unroll
    for (int i = 0; i < 2; ++i) {
      gload16(pas + i * 2048 + t * 8, sA + i * 4096 + w * 1024);
      gload16(pbs + i * 2048 + t * 8, sB + i * 4096 + w * 1024);
    }
    __syncthreads();
    #pragma unroll
    for (int kk = 0; kk < 2; ++kk) {
      v8s af[2], bfr[2];
      #pragma unroll
      for (int mf = 0; mf < 2; ++mf)
        af[mf]  = *(const v8s*)(sA + ((kk*4 + fg) * 64 + wm*32 + mf*16 + fr) * 16);
      #pragma unroll
      for (int nf = 0; nf < 2; ++nf)
        bfr[nf] = *(const v8s*)(sB + ((kk*4 + fg) * 64 + wn*32 + nf*16 + fr) * 16);
      #pragma unroll
      for (int mf = 0; mf < 2; ++mf)
        #pragma unroll
        for (int nf = 0; nf < 2; ++nf)
          acc[mf][nf] = __builtin_amdgcn_mfma_f32_16x16x32_bf16(af[mf], bfr[nf], acc[mf][nf], 0, 0, 0);
    }
    __syncthreads();
  }

  #pragma unroll
  for (int nf = 0; nf < 2; ++nf) {
    const int c = n0 + wn*32 + nf*16 + fr;
    const float bo = bo_[(size_t)e * DIM + c];
    #pragma unroll
    for (int mf = 0; mf < 2; ++mf)
      #pragma unroll
      for (int jj = 0; jj < 4; ++jj) {
        const int r = wm*32 + mf*16 + fg*4 + jj;
        if (m0 + r < cnt)
          out[(size_t)perm[off + m0 + r] * DIM + c] = acc[mf][nf][jj] + bo;
      }
  }
}

// ================= fallback path (round-1 verified kernels) =================
__global__ __launch_bounds__(256, 2) void gemm1_fb(
    const float* __restrict__ x,
    const float* __restrict__ wg_, const float* __restrict__ bg_,
    const float* __restrict__ wi_, const float* __restrict__ bi_,
    const int* __restrict__ meta, const int* __restrict__ perm,
    unsigned short* __restrict__ hbuf)
{
  constexpr int ROWB = 144;
  const int e = blockIdx.z;
  const int cnt = meta[e];
  const int m0 = blockIdx.y * 128;
  if (m0 >= cnt) return;
  const int off = meta[NEXP + e];
  const int n0 = blockIdx.x * 128;
  __shared__ __align__(16) unsigned char sA[128 * ROWB];
  __shared__ __align__(16) unsigned char sG[128 * ROWB];
  __shared__ __align__(16) unsigned char sI[128 * ROWB];
  const int t = threadIdx.x;
  const int l = t & 63, w = t >> 6;
  const int wm = w >> 1, wn = w & 1;
  const int fr = l & 15, fg = l >> 4;
  const int ar = t >> 1, ah = t & 1;
  const float* asrc = nullptr;
  if (m0 + ar < cnt) asrc = x + (size_t)perm[off + m0 + ar] * DIM + ah * 32;
  const int bl = l & 7, bk = l >> 3;
  const float* wg = wg_ + (size_t)e * DIM * HID;
  const float* wi = wi_ + (size_t)e * DIM * HID;
  v4f accG[4][4], accI[4][4];
  #pragma unroll
  for (int i = 0; i < 4; ++i)
    #pragma unroll
    for (int q = 0; q < 4; ++q) {
      accG[i][q] = (v4f){0.f, 0.f, 0.f, 0.f};
      accI[i][q] = (v4f){0.f, 0.f, 0.f, 0.f};
    }
  for (int k0 = 0; k0 < DIM; k0 += 64) {
    {
      float f[32];
      if (asrc) {
        const float4* p = (const float4*)(asrc + k0);
        #pragma unroll
        for (int q = 0; q < 8; ++q) {
          float4 v = p[q];
          f[4*q] = v.x; f[4*q+1] = v.y; f[4*q+2] = v.z; f[4*q+3] = v.w;
        }
      } else {
        #pragma unroll
        for (int q = 0; q < 32; ++q) f[q] = 0.f;
      }
      #pragma unroll
      for (int jj = 0; jj < 4; ++jj) {
        v8s r;
        #pragma unroll
        for (int q = 0; q < 8; ++q) r[q] = (short)f2bf(f[8*jj + q]);
        *(v8s*)(sA + ar * ROWB + ah * 64 + jj * 16) = r;
      }
    }
    #pragma unroll
    for (int p = 0; p < 8; ++p) {
      const int n  = bl + 8 * (w + 4 * (p & 3));
      const int kq = bk + 8 * (p >> 2);
      const size_t go = (size_t)(k0 + kq * 4) * HID + n0 + n;
      {
        const float* sp = wg + go;
        unsigned lo = f2bf(sp[0])       | ((unsigned)f2bf(sp[HID])   << 16);
        unsigned hi = f2bf(sp[2 * HID]) | ((unsigned)f2bf(sp[3*HID]) << 16);
        *(uint2*)(sG + n * ROWB + kq * 8) = make_uint2(lo, hi);
      }
      {
        const float* sp = wi + go;
        unsigned lo = f2bf(sp[0])       | ((unsigned)f2bf(sp[HID])   << 16);
        unsigned hi = f2bf(sp[2 * HID]) | ((unsigned)f2bf(sp[3*HID]) << 16);
        *(uint2*)(sI + n * ROWB + kq * 8) = make_uint2(lo, hi);
      }
    }
    __syncthreads();
    #pragma unroll
    for (int kk = 0; kk < 2; ++kk) {
      v8s af[4], gf[4], inf[4];
      #pragma unroll
      for (int mf = 0; mf < 4; ++mf)
        af[mf] = *(const v8s*)(sA + (wm*64 + mf*16 + fr) * ROWB + kk*64 + fg*16);
      #pragma unroll
      for (int nf = 0; nf < 4; ++nf) {
        gf[nf]  = *(const v8s*)(sG + (wn*64 + nf*16 + fr) * ROWB + kk*64 + fg*16);
        inf[nf] = *(const v8s*)(sI + (wn*64 + nf*16 + fr) * ROWB + kk*64 + fg*16);
      }
      #pragma unroll
      for (int mf = 0; mf < 4; ++mf)
        #pragma unroll
        for (int nf = 0; nf < 4; ++nf) {
          accG[mf][nf] = __builtin_amdgcn_mfma_f32_16x16x32_bf16(af[mf], gf[nf],  accG[mf][nf], 0, 0, 0);
          accI[mf][nf] = __builtin_amdgcn_mfma_f32_16x16x32_bf16(af[mf], inf[nf], accI[mf][nf], 0, 0, 0);
        }
    }
    __syncthreads();
  }
  #pragma unroll
  for (int nf = 0; nf < 4; ++nf) {
    const int c = n0 + wn*64 + nf*16 + fr;
    const float bg = bg_[(size_t)e * HID + c];
    const float bi = bi_[(size_t)e * HID + c];
    #pragma unroll
    for (int mf = 0; mf < 4; ++mf)
      #pragma unroll
      for (int jj = 0; jj < 4; ++jj) {
        const int r = m0 + wm*64 + mf*16 + fg*4 + jj;
        if (r < cnt) {
          const float g = accG[mf][nf][jj] + bg;
          const float v = accI[mf][nf][jj] + bi;
          const float hval = g / (1.f + __expf(-g)) * v;
          hbuf[(size_t)(off + r) * HID + c] = f2bf(hval);
        }
      }
  }
}

__global__ __launch_bounds__(256, 4) void gemm2_fb(
    const unsigned short* __restrict__ hbuf,
    const float* __restrict__ wo_, const float* __restrict__ bo_,
    const int* __restrict__ meta, const int* __restrict__ perm,
    float* __restrict__ out)
{
  constexpr int ROWB = 144;
  const int e = blockIdx.z;
  const int cnt = meta[e];
  const int m0 = blockIdx.y * 64;
  if (m0 >= cnt) return;
  const int off = meta[NEXP + e];
  const int n0 = blockIdx.x * 64;
  __shared__ __align__(16) unsigned char sA[64 * ROWB];
  __shared__ __align__(16) unsigned char sB[64 * ROWB];
  const int t = threadIdx.x;
  const int l = t & 63, w = t >> 6;
  const int wm = w >> 1, wn = w & 1;
  const int fr = l & 15, fg = l >> 4;
  const int ar = t >> 2, aq = t & 3;
  const unsigned short* asrc = nullptr;
  if (m0 + ar < cnt) asrc = hbuf + (size_t)(off + m0 + ar) * HID + aq * 16;
  const int bl = l & 7, bk = l >> 3;
  const float* wo = wo_ + (size_t)e * HID * DIM;
  v4f acc[2][2];
  #pragma unroll
  for (int i = 0; i < 2; ++i)
    #pragma unroll
    for (int q = 0; q < 2; ++q) acc[i][q] = (v4f){0.f, 0.f, 0.f, 0.f};
  for (int k0 = 0; k0 < HID; k0 += 64) {
    {
      uint4 u0 = make_uint4(0,0,0,0), u1 = make_uint4(0,0,0,0);
      if (asrc) {
        const uint4* p = (const uint4*)(asrc + k0);
        u0 = p[0]; u1 = p[1];
      }
      *(uint4*)(sA + ar * ROWB + aq * 32)      = u0;
      *(uint4*)(sA + ar * ROWB + aq * 32 + 16) = u1;
    }
    #pragma unroll
    for (int p = 0; p < 4; ++p) {
      const int n  = bl + 8 * (w + 4 * (p & 1));
      const int kq = bk + 8 * (p >> 1);
      const float* sp = wo + (size_t)(k0 + kq * 4) * DIM + n0 + n;
      unsigned lo = f2bf(sp[0])       | ((unsigned)f2bf(sp[DIM])   << 16);
      unsigned hi = f2bf(sp[2 * DIM]) | ((unsigned)f2bf(sp[3*DIM]) << 16);
      *(uint2*)(sB + n * ROWB + kq * 8) = make_uint2(lo, hi);
    }
    __syncthreads();
    #pragma unroll
    for (int kk = 0; kk < 2; ++kk) {
      v8s af[2], bfr[2];
      #pragma unroll
      for (int mf = 0; mf < 2; ++mf)
        af[mf]  = *(const v8s*)(sA + (wm*32 + mf*16 + fr) * ROWB + kk*64 + fg*16);
      #pragma unroll
      for (int nf = 0; nf < 2; ++nf)
        bfr[nf] = *(const v8s*)(sB + (wn*32 + nf*16 + fr) * ROWB + kk*64 + fg*16);
      #pragma unroll
      for (int mf = 0; mf < 2; ++mf)
        #pragma unroll
        for (int nf = 0; nf < 2; ++nf)
          acc[mf][nf] = __builtin_amdgcn_mfma_f32_16x16x32_bf16(af[mf], bfr[nf], acc[mf][nf], 0, 0, 0);
    }
    __syncthreads();
  }
  #pragma unroll
  for (int nf = 0; nf < 2; ++nf) {
    const int c = n0 + wn*32 + nf*16 + fr;
    const float bo = bo_[(size_t)e * DIM + c];
    #pragma unroll
    for (int mf = 0; mf < 2; ++mf)
      #pragma unroll
      for (int jj = 0; jj < 4; ++jj) {
        const int r = m0 + wm*32 + mf*16 + fg*4 + jj;
        if (r < cnt)
          out[(size_t)perm[off + r] * DIM + c] = acc[mf][nf][jj] + bo;
      }
  }
}

// ---------------- launch ----------------
extern "C" void kernel_launch(void* const* d_in, const int* in_sizes, int n_in,
                              void* d_out, int out_size, void* d_ws, size_t ws_size,
                              hipStream_t stream) {
  const float* x      = (const float*)d_in[0];
  const int*   route  = (const int*)d_in[1];
  const float* w_in   = (const float*)d_in[2];
  const float* b_in   = (const float*)d_in[3];
  const float* w_gate = (const float*)d_in[4];
  const float* b_gate = (const float*)d_in[5];
  const float* w_out  = (const float*)d_in[6];
  const float* b_out  = (const float*)d_in[7];
  float* out = (float*)d_out;

  const int ntok = in_sizes[1];  // 4096

  int* meta = (int*)d_ws;
  int* perm = (int*)((char*)d_ws + 128);

  const size_t WGP_OFF = 32768;
  const size_t WMAT_BYTES = (size_t)NEXP * DIM * HID * 2;   // 16777216 per matrix (bf16)
  const size_t HBUF_ROWS = 5120;                            // 4096 + 8*128 headroom
  const size_t NEED = WGP_OFF + 3 * WMAT_BYTES + HBUF_ROWS * HID * 2;

  route_prep<<<1, 256, 0, stream>>>(route, meta, ntok);
  fill_perm<<<(ntok + 255) / 256, 256, 0, stream>>>(route, meta, perm, ntok);

  if (ws_size >= NEED) {
    unsigned short* wgp  = (unsigned short*)((char*)d_ws + WGP_OFF);
    unsigned short* wip  = (unsigned short*)((char*)d_ws + WGP_OFF + WMAT_BYTES);
    unsigned short* wop  = (unsigned short*)((char*)d_ws + WGP_OFF + 2 * WMAT_BYTES);
    unsigned short* hbuf = (unsigned short*)((char*)d_ws + WGP_OFF + 3 * WMAT_BYTES);

    wgi_conv<<<dim3(8, 16, 16), 256, 0, stream>>>(w_gate, w_in, wgp, wip);
    wo_conv<<<dim3(32, 8, 8), 256, 0, stream>>>(w_out, wop);
    gemm1<<<dim3(16, (ntok + 127) / 128, NEXP), 256, 0, stream>>>(
        x, wgp, b_gate, wip, b_in, meta, perm, hbuf);
    gemm2<<<dim3(8, (ntok + 63) / 64, NEXP), 256, 0, stream>>>(
        hbuf, wop, b_out, meta, perm, out);
  } else {
    unsigned short* hbuf = (unsigned short*)((char*)d_ws + 32768);
    gemm1_fb<<<dim3(HID / 128, (ntok + 127) / 128, NEXP), 256, 0, stream>>>(
        x, w_gate, b_gate, w_in, b_in, meta, perm, hbuf);
    gemm2_fb<<<dim3(DIM / 64, (ntok + 63) / 64, NEXP), 256, 0, stream>>>(
        hbuf, w_out, b_out, meta, perm, out);
  }
}

// Round 3
// 126.211 us; speedup vs baseline: 1.8282x; 1.2410x over previous
//
#include <hip/hip_runtime.h>

#define DIM 512
#define HID 2048
#define NEXP 8

typedef __attribute__((ext_vector_type(8))) short v8s;   // 8 x bf16 bits
typedef __attribute__((ext_vector_type(4))) float v4f;   // MFMA accumulator

__device__ __forceinline__ unsigned short f2bf(float f) {
  union { __bf16 b; unsigned short u; } c;
  c.b = (__bf16)f;
  return c.u;
}

__device__ __forceinline__ void gload16(const void* g, void* l) {
  __builtin_amdgcn_global_load_lds(
      (const __attribute__((address_space(1))) unsigned int*)g,
      (__attribute__((address_space(3))) unsigned int*)l, 16, 0, 0);
}

// ---------------- routing prep ----------------
__global__ void route_prep(const int* __restrict__ route, int* __restrict__ meta, int ntok) {
  __shared__ int c[NEXP];
  int t = threadIdx.x;
  if (t < NEXP) c[t] = 0;
  __syncthreads();
  for (int n = t; n < ntok; n += blockDim.x) atomicAdd(&c[route[n]], 1);
  __syncthreads();
  if (t == 0) {
    int acc = 0, pacc = 0;
    for (int e = 0; e < NEXP; ++e) {
      meta[e] = c[e];            // count
      meta[NEXP + e] = acc;      // exact offset
      meta[2 * NEXP + e] = acc;  // cursor for fill_perm
      meta[3 * NEXP + e] = pacc; // 128-padded offset (hbuf panel rows)
      acc += c[e];
      pacc += ((c[e] + 127) >> 7) << 7;
    }
  }
}

__global__ void fill_perm(const int* __restrict__ route, int* __restrict__ meta,
                          int* __restrict__ perm, int ntok) {
  int n = blockIdx.x * blockDim.x + threadIdx.x;
  if (n < ntok) {
    int p = atomicAdd(&meta[2 * NEXP + route[n]], 1);
    perm[p] = n;
  }
}

// ---------------- weight conversion to bf16 panels ----------------
// Panel layout per (e, n-stripe): element (n, k) at ushort ((k>>3)*R + n)*8 + (k&7).
// BK-agnostic: any 64/32-wide K-step is a contiguous chunk. gload16-ready.

// wg/wi: R=128, per (e,j): 65536 ushorts.
__global__ __launch_bounds__(256) void wgi_conv(
    const float* __restrict__ wg, const float* __restrict__ wi,
    unsigned short* __restrict__ wgp, unsigned short* __restrict__ wip)
{
  const int s = blockIdx.x;            // 64-K chunk (8)
  const int j = blockIdx.y;            // n-stripe (16)
  const int e = blockIdx.z >> 1;
  const int which = blockIdx.z & 1;
  const float* src = (which ? wi : wg) + (size_t)e * DIM * HID;
  unsigned short* dst = (which ? wip : wgp) + (((size_t)e * 16 + j) * 8 + s) * 8192;
  const int t = threadIdx.x;
  #pragma unroll
  for (int i = 0; i < 4; ++i) {
    const int c = t + 256 * i;         // chunk in [0,1024)
    const int kq = c >> 7, n = c & 127;
    const float* srow = src + (size_t)(s * 64 + kq * 8) * HID + j * 128 + n;
    v8s r;
    #pragma unroll
    for (int q = 0; q < 8; ++q) r[q] = (short)f2bf(srow[(size_t)q * HID]);
    *(v8s*)(dst + (size_t)c * 8) = r;
  }
}

// w_out: R=64, per (e,j): 131072 ushorts.
__global__ __launch_bounds__(256) void wo_conv(
    const float* __restrict__ wo, unsigned short* __restrict__ wop)
{
  const int s = blockIdx.x;            // 64-K chunk (32)
  const int j = blockIdx.y;            // n-stripe (8)
  const int e = blockIdx.z;
  const float* src = wo + (size_t)e * HID * DIM;
  unsigned short* dst = wop + (((size_t)e * 8 + j) * 32 + s) * 4096;
  const int t = threadIdx.x;
  #pragma unroll
  for (int i = 0; i < 2; ++i) {
    const int c = t + 256 * i;         // chunk in [0,512)
    const int kq = c >> 6, n = c & 63;
    const float* srow = src + (size_t)(s * 64 + kq * 8) * DIM + j * 64 + n;
    v8s r;
    #pragma unroll
    for (int q = 0; q < 8; ++q) r[q] = (short)f2bf(srow[(size_t)q * DIM]);
    *(v8s*)(dst + (size_t)c * 8) = r;
  }
}

// ---------------- GEMM1: h = silu(x@wg+bg)*(x@wi+bi) -> hbuf panels ----------------
// BM=128, BN=128, BK=32, 256 thr (4 waves 2x2, 64x64/wave).
// Double-buffered LDS (2 x 24KB), prefetch-before-compute (T3 2-phase),
// A-cvt split issue-early/write-late (T14). 1D grid, e = bid&7 (T1 XCD swizzle).
__global__ __launch_bounds__(256, 2) void gemm1(
    const float* __restrict__ x,
    const unsigned short* __restrict__ wgp, const float* __restrict__ bg_,
    const unsigned short* __restrict__ wip, const float* __restrict__ bi_,
    const int* __restrict__ meta, const int* __restrict__ perm,
    unsigned short* __restrict__ hbuf)
{
  const int bid = blockIdx.x;
  const int e = bid & 7;
  const int r_ = bid >> 3;
  const int j = r_ & 15;
  const int mt = r_ >> 4;
  const int cnt = meta[e];
  const int m0 = mt * 128;
  if (m0 >= cnt) return;
  const int off  = meta[NEXP + e];
  const int poff = meta[3 * NEXP + e];
  const int n0 = j * 128;

  // [buf 0/1][ sA 8K | sG 8K | sI 8K ]
  __shared__ __align__(16) unsigned char lds[49152];

  const int t = threadIdx.x;
  const int l = t & 63, w = t >> 6;
  const int wm = w >> 1, wn = w & 1;
  const int fr = l & 15, fg = l >> 4;

  // A staging: 2 thr/row, 16 floats each (half of the 32-wide K-step)
  const int ar = t >> 1, ah = t & 1;
  int arow = m0 + ar; if (arow >= cnt) arow = cnt - 1;   // clamp; tail rows discarded
  const float* asrc = x + (size_t)perm[off + arow] * DIM + ah * 16;

  const unsigned short* pg = wgp + ((size_t)e * 16 + j) * 65536;
  const unsigned short* pi = wip + ((size_t)e * 16 + j) * 65536;

  v4f accG[4][4], accI[4][4];
  #pragma unroll
  for (int i = 0; i < 4; ++i)
    #pragma unroll
    for (int q = 0; q < 4; ++q) {
      accG[i][q] = (v4f){0.f, 0.f, 0.f, 0.f};
      accI[i][q] = (v4f){0.f, 0.f, 0.f, 0.f};
    }

  // --- staging helpers (s = 32-wide K-step, b = buffer) ---
  auto stage_w = [&](int s, int b) {
    unsigned char* base = lds + b * 24576;
    const unsigned short* pgs = pg + (size_t)s * 4096;
    const unsigned short* pis = pi + (size_t)s * 4096;
    gload16(pgs + t * 8,        base + 8192 + w * 1024);
    gload16(pgs + 2048 + t * 8, base + 8192 + 4096 + w * 1024);
    gload16(pis + t * 8,        base + 16384 + w * 1024);
    gload16(pis + 2048 + t * 8, base + 16384 + 4096 + w * 1024);
  };

  float4 a0, a1, a2, a3;
  auto stage_a_load = [&](int s) {
    const float4* p = (const float4*)(asrc + s * 32);
    a0 = p[0]; a1 = p[1]; a2 = p[2]; a3 = p[3];
  };
  auto stage_a_write = [&](int b) {
    unsigned char* base = lds + b * 24576;
    v8s r0, r1;
    r0[0] = (short)f2bf(a0.x); r0[1] = (short)f2bf(a0.y);
    r0[2] = (short)f2bf(a0.z); r0[3] = (short)f2bf(a0.w);
    r0[4] = (short)f2bf(a1.x); r0[5] = (short)f2bf(a1.y);
    r0[6] = (short)f2bf(a1.z); r0[7] = (short)f2bf(a1.w);
    r1[0] = (short)f2bf(a2.x); r1[1] = (short)f2bf(a2.y);
    r1[2] = (short)f2bf(a2.z); r1[3] = (short)f2bf(a2.w);
    r1[4] = (short)f2bf(a3.x); r1[5] = (short)f2bf(a3.y);
    r1[6] = (short)f2bf(a3.z); r1[7] = (short)f2bf(a3.w);
    *(v8s*)(base + ((ah * 2 + 0) * 128 + ar) * 16) = r0;
    *(v8s*)(base + ((ah * 2 + 1) * 128 + ar) * 16) = r1;
  };

  // prologue
  stage_w(0, 0);
  stage_a_load(0);
  stage_a_write(0);
  __syncthreads();

  int cur = 0;
  for (int s = 0; s < 16; ++s) {
    if (s < 15) {            // issue next-tile global traffic BEFORE compute
      stage_w(s + 1, cur ^ 1);
      stage_a_load(s + 1);
    }
    unsigned char* base = lds + cur * 24576;
    v8s af[4], gf[4], inf[4];
    #pragma unroll
    for (int mf = 0; mf < 4; ++mf)
      af[mf] = *(const v8s*)(base + (fg * 128 + wm * 64 + mf * 16 + fr) * 16);
    #pragma unroll
    for (int nf = 0; nf < 4; ++nf) {
      gf[nf]  = *(const v8s*)(base + 8192  + (fg * 128 + wn * 64 + nf * 16 + fr) * 16);
      inf[nf] = *(const v8s*)(base + 16384 + (fg * 128 + wn * 64 + nf * 16 + fr) * 16);
    }
    #pragma unroll
    for (int mf = 0; mf < 4; ++mf)
      #pragma unroll
      for (int nf = 0; nf < 4; ++nf) {
        accG[mf][nf] = __builtin_amdgcn_mfma_f32_16x16x32_bf16(af[mf], gf[nf],  accG[mf][nf], 0, 0, 0);
        accI[mf][nf] = __builtin_amdgcn_mfma_f32_16x16x32_bf16(af[mf], inf[nf], accI[mf][nf], 0, 0, 0);
      }
    if (s < 15) stage_a_write(cur ^ 1);  // cvt+ds_write after MFMA (latency hidden)
    __syncthreads();
    cur ^= 1;
  }

  // epilogue: bias + SiLU(gate)*in -> hbuf panels (bf16)
  #pragma unroll
  for (int nf = 0; nf < 4; ++nf) {
    const int c = n0 + wn * 64 + nf * 16 + fr;      // k-dim of gemm2
    const float bg = bg_[(size_t)e * HID + c];
    const float bi = bi_[(size_t)e * HID + c];
    #pragma unroll
    for (int mf = 0; mf < 4; ++mf)
      #pragma unroll
      for (int jj = 0; jj < 4; ++jj) {
        const int r = wm * 64 + mf * 16 + fg * 4 + jj;   // local row
        if (m0 + r < cnt) {
          const float g = accG[mf][nf][jj] + bg;
          const float v = accI[mf][nf][jj] + bi;
          const float hval = g / (1.f + __expf(-g)) * v;
          const int grow = poff + m0 + r;                 // padded global row
          hbuf[(size_t)(grow >> 6) * 131072 + ((size_t)(c >> 3) * 64 + (grow & 63)) * 8 + (c & 7)] = f2bf(hval);
        }
      }
  }
}

// ---------------- GEMM2: out[perm] = h @ w_out + b_out ----------------
// BM=64, BN=64, BK=64, 256 thr (4 waves 2x2, 32x32/wave).
// Double-buffered (2 x 16KB), prefetch-before-compute, both operands via gload16.
__global__ __launch_bounds__(256, 4) void gemm2(
    const unsigned short* __restrict__ hbuf,
    const unsigned short* __restrict__ wop, const float* __restrict__ bo_,
    const int* __restrict__ meta, const int* __restrict__ perm,
    float* __restrict__ out)
{
  const int bid = blockIdx.x;
  const int e = bid & 7;
  const int r_ = bid >> 3;
  const int jn = r_ & 7;
  const int mt = r_ >> 3;
  const int cnt = meta[e];
  const int m0 = mt * 64;
  if (m0 >= cnt) return;
  const int off  = meta[NEXP + e];
  const int poff = meta[3 * NEXP + e];
  const int n0 = jn * 64;

  // [buf 0/1][ sA 8K | sB 8K ]
  __shared__ __align__(16) unsigned char lds[32768];

  const int t = threadIdx.x;
  const int l = t & 63, w = t >> 6;
  const int wm = w >> 1, wn = w & 1;
  const int fr = l & 15, fg = l >> 4;

  const unsigned short* pa = hbuf + (size_t)((poff + m0) >> 6) * 131072;
  const unsigned short* pb = wop + ((size_t)e * 8 + jn) * 131072;

  v4f acc[2][2];
  #pragma unroll
  for (int i = 0; i < 2; ++i)
    #pragma unroll
    for (int q = 0; q < 2; ++q) acc[i][q] = (v4f){0.f, 0.f, 0.f, 0.f};

  auto stage = [&](int s, int b) {
    unsigned char* base = lds + b * 16384;
    const unsigned short* pas = pa + (size_t)s * 4096;
    const unsigned short* pbs = pb + (size_t)s * 4096;
    gload16(pas + t * 8,        base + w * 1024);
    gload16(pas + 2048 + t * 8, base + 4096 + w * 1024);
    gload16(pbs + t * 8,        base + 8192 + w * 1024);
    gload16(pbs + 2048 + t * 8, base + 8192 + 4096 + w * 1024);
  };

  stage(0, 0);
  __syncthreads();

  int cur = 0;
  for (int s = 0; s < 32; ++s) {
    if (s < 31) stage(s + 1, cur ^ 1);
    unsigned char* base = lds + cur * 16384;
    v8s af[2][2], bf2[2][2];
    #pragma unroll
    for (int kk = 0; kk < 2; ++kk) {
      #pragma unroll
      for (int mf = 0; mf < 2; ++mf)
        af[kk][mf]  = *(const v8s*)(base + ((kk * 4 + fg) * 64 + wm * 32 + mf * 16 + fr) * 16);
      #pragma unroll
      for (int nf = 0; nf < 2; ++nf)
        bf2[kk][nf] = *(const v8s*)(base + 8192 + ((kk * 4 + fg) * 64 + wn * 32 + nf * 16 + fr) * 16);
    }
    #pragma unroll
    for (int kk = 0; kk < 2; ++kk)
      #pragma unroll
      for (int mf = 0; mf < 2; ++mf)
        #pragma unroll
        for (int nf = 0; nf < 2; ++nf)
          acc[mf][nf] = __builtin_amdgcn_mfma_f32_16x16x32_bf16(af[kk][mf], bf2[kk][nf], acc[mf][nf], 0, 0, 0);
    __syncthreads();
    cur ^= 1;
  }

  #pragma unroll
  for (int nf = 0; nf < 2; ++nf) {
    const int c = n0 + wn * 32 + nf * 16 + fr;
    const float bo = bo_[(size_t)e * DIM + c];
    #pragma unroll
    for (int mf = 0; mf < 2; ++mf)
      #pragma unroll
      for (int jj = 0; jj < 4; ++jj) {
        const int r = wm * 32 + mf * 16 + fg * 4 + jj;
        if (m0 + r < cnt)
          out[(size_t)perm[off + m0 + r] * DIM + c] = acc[mf][nf][jj] + bo;
      }
  }
}

// ---------------- launch ----------------
extern "C" void kernel_launch(void* const* d_in, const int* in_sizes, int n_in,
                              void* d_out, int out_size, void* d_ws, size_t ws_size,
                              hipStream_t stream) {
  const float* x      = (const float*)d_in[0];
  const int*   route  = (const int*)d_in[1];
  const float* w_in   = (const float*)d_in[2];
  const float* b_in   = (const float*)d_in[3];
  const float* w_gate = (const float*)d_in[4];
  const float* b_gate = (const float*)d_in[5];
  const float* w_out  = (const float*)d_in[6];
  const float* b_out  = (const float*)d_in[7];
  float* out = (float*)d_out;

  const int ntok = in_sizes[1];  // 4096

  int* meta = (int*)d_ws;
  int* perm = (int*)((char*)d_ws + 128);

  const size_t WGP_OFF = 32768;
  const size_t WMAT_BYTES = (size_t)NEXP * DIM * HID * 2;   // 16 MiB per matrix (bf16)

  unsigned short* wgp  = (unsigned short*)((char*)d_ws + WGP_OFF);
  unsigned short* wip  = (unsigned short*)((char*)d_ws + WGP_OFF + WMAT_BYTES);
  unsigned short* wop  = (unsigned short*)((char*)d_ws + WGP_OFF + 2 * WMAT_BYTES);
  unsigned short* hbuf = (unsigned short*)((char*)d_ws + WGP_OFF + 3 * WMAT_BYTES);

  const int MT1 = (ntok + 127) / 128;
  const int MT2 = (ntok + 63) / 64;

  route_prep<<<1, 256, 0, stream>>>(route, meta, ntok);
  fill_perm<<<(ntok + 255) / 256, 256, 0, stream>>>(route, meta, perm, ntok);
  wgi_conv<<<dim3(8, 16, 16), 256, 0, stream>>>(w_gate, w_in, wgp, wip);
  wo_conv<<<dim3(32, 8, 8), 256, 0, stream>>>(w_out, wop);
  gemm1<<<NEXP * 16 * MT1, 256, 0, stream>>>(
      x, wgp, b_gate, wip, b_in, meta, perm, hbuf);
  gemm2<<<NEXP * 8 * MT2, 256, 0, stream>>>(
      hbuf, wop, b_out, meta, perm, out);
}

// Round 4
// 112.923 us; speedup vs baseline: 2.0434x; 1.1177x over previous
//
#include <hip/hip_runtime.h>

#define DIM 512
#define HID 2048
#define NEXP 8

typedef __attribute__((ext_vector_type(8))) short v8s;   // 8 x bf16 bits
typedef __attribute__((ext_vector_type(4))) float v4f;   // MFMA accumulator

__device__ __forceinline__ unsigned short f2bf(float f) {
  union { __bf16 b; unsigned short u; } c;
  c.b = (__bf16)f;
  return c.u;
}

__device__ __forceinline__ void gload16(const void* g, void* l) {
  __builtin_amdgcn_global_load_lds(
      (const __attribute__((address_space(1))) unsigned int*)g,
      (__attribute__((address_space(3))) unsigned int*)l, 16, 0, 0);
}

// ---------------- routing prep ----------------
__global__ void route_prep(const int* __restrict__ route, int* __restrict__ meta, int ntok) {
  __shared__ int c[NEXP];
  int t = threadIdx.x;
  if (t < NEXP) c[t] = 0;
  __syncthreads();
  for (int n = t; n < ntok; n += blockDim.x) atomicAdd(&c[route[n]], 1);
  __syncthreads();
  if (t == 0) {
    int acc = 0, pacc = 0;
    for (int e = 0; e < NEXP; ++e) {
      meta[e] = c[e];            // count
      meta[NEXP + e] = acc;      // exact offset
      meta[2 * NEXP + e] = acc;  // cursor for fill_perm
      meta[3 * NEXP + e] = pacc; // 128-padded offset (panel rows)
      acc += c[e];
      pacc += ((c[e] + 127) >> 7) << 7;
    }
  }
}

__global__ void fill_perm(const int* __restrict__ route, int* __restrict__ meta,
                          int* __restrict__ perm, int ntok) {
  int n = blockIdx.x * blockDim.x + threadIdx.x;
  if (n < ntok) {
    int p = atomicAdd(&meta[2 * NEXP + route[n]], 1);
    perm[p] = n;
  }
}

// ---------------- weight conversion to bf16 panels ----------------
// Panel layout per (e, n-stripe): element (n, k) at ushort ((k>>3)*R + n)*8 + (k&7).

// wg/wi: R=128, per (e,j): 65536 ushorts.
__global__ __launch_bounds__(256) void wgi_conv(
    const float* __restrict__ wg, const float* __restrict__ wi,
    unsigned short* __restrict__ wgp, unsigned short* __restrict__ wip)
{
  const int s = blockIdx.x;            // 64-K chunk (8)
  const int j = blockIdx.y;            // n-stripe (16)
  const int e = blockIdx.z >> 1;
  const int which = blockIdx.z & 1;
  const float* src = (which ? wi : wg) + (size_t)e * DIM * HID;
  unsigned short* dst = (which ? wip : wgp) + (((size_t)e * 16 + j) * 8 + s) * 8192;
  const int t = threadIdx.x;
  #pragma unroll
  for (int i = 0; i < 4; ++i) {
    const int c = t + 256 * i;         // chunk in [0,1024)
    const int kq = c >> 7, n = c & 127;
    const float* srow = src + (size_t)(s * 64 + kq * 8) * HID + j * 128 + n;
    v8s r;
    #pragma unroll
    for (int q = 0; q < 8; ++q) r[q] = (short)f2bf(srow[(size_t)q * HID]);
    *(v8s*)(dst + (size_t)c * 8) = r;
  }
}

// w_out: R=64, per (e,j): 131072 ushorts.
__global__ __launch_bounds__(256) void wo_conv(
    const float* __restrict__ wo, unsigned short* __restrict__ wop)
{
  const int s = blockIdx.x;            // 64-K chunk (32)
  const int j = blockIdx.y;            // n-stripe (8)
  const int e = blockIdx.z;
  const float* src = wo + (size_t)e * HID * DIM;
  unsigned short* dst = wop + (((size_t)e * 8 + j) * 32 + s) * 4096;
  const int t = threadIdx.x;
  #pragma unroll
  for (int i = 0; i < 2; ++i) {
    const int c = t + 256 * i;         // chunk in [0,512)
    const int kq = c >> 6, n = c & 63;
    const float* srow = src + (size_t)(s * 64 + kq * 8) * DIM + j * 64 + n;
    v8s r;
    #pragma unroll
    for (int q = 0; q < 8; ++q) r[q] = (short)f2bf(srow[(size_t)q * DIM]);
    *(v8s*)(dst + (size_t)c * 8) = r;
  }
}

// ---------------- x conversion: gathered bf16 A-panels ----------------
// xp per 64-row tile: [kq 0..63][row 0..63][8k] bf16 = 32768 ushorts (64 KB).
__global__ __launch_bounds__(256) void x_conv(
    const float* __restrict__ x, const int* __restrict__ meta,
    const int* __restrict__ perm, unsigned short* __restrict__ xp)
{
  const int bid = blockIdx.x;
  const int e = bid & 7;
  const int mt = bid >> 3;
  const int cnt = meta[e];
  if (mt * 64 >= cnt) return;
  const int off  = meta[NEXP + e];
  const int poff = meta[3 * NEXP + e];
  const int t = threadIdx.x;
  const int r = t & 63, q = t >> 6;          // row, quarter (128 floats)
  int arow = mt * 64 + r; if (arow >= cnt) arow = cnt - 1;
  const float* src = x + (size_t)perm[off + arow] * DIM + q * 128;
  unsigned short* dst = xp + (size_t)((poff + mt * 64) >> 6) * 32768;
  #pragma unroll
  for (int j = 0; j < 16; ++j) {
    float4 f0 = ((const float4*)src)[2 * j];
    float4 f1 = ((const float4*)src)[2 * j + 1];
    v8s v;
    v[0] = (short)f2bf(f0.x); v[1] = (short)f2bf(f0.y);
    v[2] = (short)f2bf(f0.z); v[3] = (short)f2bf(f0.w);
    v[4] = (short)f2bf(f1.x); v[5] = (short)f2bf(f1.y);
    v[6] = (short)f2bf(f1.z); v[7] = (short)f2bf(f1.w);
    *(v8s*)(dst + (size_t)((q * 16 + j) * 64 + r) * 8) = v;
  }
}

// ---------------- GEMM1: h = silu(x@wg+bg)*(x@wi+bi) -> hbuf panels ----------------
// BM=64, BN=128, BK=32, 256 thr (4 waves 2x2: 32x64 per wave).
// Pure global_load_lds staging (5/thread/step), dbuf 2x20KB, 1 barrier/step.
__global__ __launch_bounds__(256, 4) void gemm1(
    const unsigned short* __restrict__ xp,
    const unsigned short* __restrict__ wgp, const float* __restrict__ bg_,
    const unsigned short* __restrict__ wip, const float* __restrict__ bi_,
    const int* __restrict__ meta,
    unsigned short* __restrict__ hbuf)
{
  const int bid = blockIdx.x;
  const int e = bid & 7;
  const int r_ = bid >> 3;
  const int j = r_ & 15;
  const int mt = r_ >> 4;
  const int cnt = meta[e];
  const int m0 = mt * 64;
  if (m0 >= cnt) return;
  const int poff = meta[3 * NEXP + e];
  const int n0 = j * 128;

  // per buf (20480 B): A @0 (4K) | G @4096 (8K) | I @12288 (8K)
  __shared__ __align__(16) unsigned char lds[40960];

  const int t = threadIdx.x;
  const int l = t & 63, w = t >> 6;
  const int wm = w >> 1, wn = w & 1;
  const int fr = l & 15, fg = l >> 4;

  const unsigned short* pa = xp + (size_t)((poff + m0) >> 6) * 32768;
  const unsigned short* pg = wgp + ((size_t)e * 16 + j) * 65536;
  const unsigned short* pi = wip + ((size_t)e * 16 + j) * 65536;

  v4f accG[2][4], accI[2][4];
  #pragma unroll
  for (int i = 0; i < 2; ++i)
    #pragma unroll
    for (int q = 0; q < 4; ++q) {
      accG[i][q] = (v4f){0.f, 0.f, 0.f, 0.f};
      accI[i][q] = (v4f){0.f, 0.f, 0.f, 0.f};
    }

  auto stage = [&](int s, int b) {
    unsigned char* base = lds + b * 20480;
    gload16(pa + (size_t)s * 2048 + t * 8,        base + w * 1024);
    gload16(pg + (size_t)s * 4096 + t * 8,        base + 4096 + w * 1024);
    gload16(pg + (size_t)s * 4096 + 2048 + t * 8, base + 8192 + w * 1024);
    gload16(pi + (size_t)s * 4096 + t * 8,        base + 12288 + w * 1024);
    gload16(pi + (size_t)s * 4096 + 2048 + t * 8, base + 16384 + w * 1024);
  };

  stage(0, 0);
  __syncthreads();

  int cur = 0;
  for (int s = 0; s < 16; ++s) {
    if (s < 15) stage(s + 1, cur ^ 1);   // prefetch BEFORE compute (T3 2-phase)
    unsigned char* base = lds + cur * 20480;
    v8s af[2], gf[4], inf[4];
    #pragma unroll
    for (int mf = 0; mf < 2; ++mf)
      af[mf] = *(const v8s*)(base + ((fg * 64) + wm * 32 + mf * 16 + fr) * 16);
    #pragma unroll
    for (int nf = 0; nf < 4; ++nf) {
      gf[nf]  = *(const v8s*)(base + 4096  + ((fg * 128) + wn * 64 + nf * 16 + fr) * 16);
      inf[nf] = *(const v8s*)(base + 12288 + ((fg * 128) + wn * 64 + nf * 16 + fr) * 16);
    }
    #pragma unroll
    for (int mf = 0; mf < 2; ++mf)
      #pragma unroll
      for (int nf = 0; nf < 4; ++nf) {
        accG[mf][nf] = __builtin_amdgcn_mfma_f32_16x16x32_bf16(af[mf], gf[nf],  accG[mf][nf], 0, 0, 0);
        accI[mf][nf] = __builtin_amdgcn_mfma_f32_16x16x32_bf16(af[mf], inf[nf], accI[mf][nf], 0, 0, 0);
      }
    __syncthreads();
    cur ^= 1;
  }

  // epilogue: bias + SiLU(gate)*in -> hbuf panels (bf16)
  const size_t tbase = (size_t)((poff + m0) >> 6) * 131072;
  #pragma unroll
  for (int nf = 0; nf < 4; ++nf) {
    const int c = n0 + wn * 64 + nf * 16 + fr;      // k-dim of gemm2
    const float bg = bg_[(size_t)e * HID + c];
    const float bi = bi_[(size_t)e * HID + c];
    #pragma unroll
    for (int mf = 0; mf < 2; ++mf)
      #pragma unroll
      for (int jj = 0; jj < 4; ++jj) {
        const int r = wm * 32 + mf * 16 + fg * 4 + jj;   // local row in [0,64)
        if (m0 + r < cnt) {
          const float g = accG[mf][nf][jj] + bg;
          const float v = accI[mf][nf][jj] + bi;
          const float hval = g / (1.f + __expf(-g)) * v;
          hbuf[tbase + (size_t)((c >> 3) * 64 + r) * 8 + (c & 7)] = f2bf(hval);
        }
      }
  }
}

// ---------------- GEMM2: out[perm] = h @ w_out + b_out ----------------
// BM=64, BN=64, BK=64, 512 thr (8 waves 2x4: 32x16 per wave), dbuf 2x16KB.
__global__ __launch_bounds__(512, 4) void gemm2(
    const unsigned short* __restrict__ hbuf,
    const unsigned short* __restrict__ wop, const float* __restrict__ bo_,
    const int* __restrict__ meta, const int* __restrict__ perm,
    float* __restrict__ out)
{
  const int bid = blockIdx.x;
  const int e = bid & 7;
  const int r_ = bid >> 3;
  const int jn = r_ & 7;
  const int mt = r_ >> 3;
  const int cnt = meta[e];
  const int m0 = mt * 64;
  if (m0 >= cnt) return;
  const int off  = meta[NEXP + e];
  const int poff = meta[3 * NEXP + e];
  const int n0 = jn * 64;

  // per buf (16384 B): A @0 (8K) | B @8192 (8K)
  __shared__ __align__(16) unsigned char lds[32768];

  const int t = threadIdx.x;
  const int l = t & 63, w = t >> 6;
  const int wm = w >> 2, wn = w & 3;
  const int fr = l & 15, fg = l >> 4;

  const unsigned short* pa = hbuf + (size_t)((poff + m0) >> 6) * 131072;
  const unsigned short* pb = wop + ((size_t)e * 8 + jn) * 131072;

  v4f acc[2];
  acc[0] = (v4f){0.f, 0.f, 0.f, 0.f};
  acc[1] = (v4f){0.f, 0.f, 0.f, 0.f};

  auto stage = [&](int s, int b) {
    unsigned char* base = lds + b * 16384;
    gload16(pa + (size_t)s * 4096 + t * 8, base + w * 1024);
    gload16(pb + (size_t)s * 4096 + t * 8, base + 8192 + w * 1024);
  };

  stage(0, 0);
  __syncthreads();

  int cur = 0;
  for (int s = 0; s < 32; ++s) {
    if (s < 31) stage(s + 1, cur ^ 1);
    unsigned char* base = lds + cur * 16384;
    v8s af[2][2], bf2[2];
    #pragma unroll
    for (int kk = 0; kk < 2; ++kk) {
      #pragma unroll
      for (int mf = 0; mf < 2; ++mf)
        af[kk][mf] = *(const v8s*)(base + ((kk * 4 + fg) * 64 + wm * 32 + mf * 16 + fr) * 16);
      bf2[kk] = *(const v8s*)(base + 8192 + ((kk * 4 + fg) * 64 + wn * 16 + fr) * 16);
    }
    #pragma unroll
    for (int kk = 0; kk < 2; ++kk)
      #pragma unroll
      for (int mf = 0; mf < 2; ++mf)
        acc[mf] = __builtin_amdgcn_mfma_f32_16x16x32_bf16(af[kk][mf], bf2[kk], acc[mf], 0, 0, 0);
    __syncthreads();
    cur ^= 1;
  }

  const int c = n0 + wn * 16 + fr;
  const float bo = bo_[(size_t)e * DIM + c];
  #pragma unroll
  for (int mf = 0; mf < 2; ++mf)
    #pragma unroll
    for (int jj = 0; jj < 4; ++jj) {
      const int r = wm * 32 + mf * 16 + fg * 4 + jj;
      if (m0 + r < cnt)
        out[(size_t)perm[off + m0 + r] * DIM + c] = acc[mf][jj] + bo;
    }
}

// ---------------- launch ----------------
extern "C" void kernel_launch(void* const* d_in, const int* in_sizes, int n_in,
                              void* d_out, int out_size, void* d_ws, size_t ws_size,
                              hipStream_t stream) {
  const float* x      = (const float*)d_in[0];
  const int*   route  = (const int*)d_in[1];
  const float* w_in   = (const float*)d_in[2];
  const float* b_in   = (const float*)d_in[3];
  const float* w_gate = (const float*)d_in[4];
  const float* b_gate = (const float*)d_in[5];
  const float* w_out  = (const float*)d_in[6];
  const float* b_out  = (const float*)d_in[7];
  float* out = (float*)d_out;

  const int ntok = in_sizes[1];  // 4096

  int* meta = (int*)d_ws;
  int* perm = (int*)((char*)d_ws + 128);

  const size_t WGP_OFF = 32768;
  const size_t WMAT_BYTES = (size_t)NEXP * DIM * HID * 2;   // 16 MiB per matrix (bf16)

  unsigned short* wgp  = (unsigned short*)((char*)d_ws + WGP_OFF);
  unsigned short* wip  = (unsigned short*)((char*)d_ws + WGP_OFF + WMAT_BYTES);
  unsigned short* wop  = (unsigned short*)((char*)d_ws + WGP_OFF + 2 * WMAT_BYTES);
  unsigned short* xp   = wop;   // aliases wop: xp consumed by gemm1, wop written after
  unsigned short* hbuf = (unsigned short*)((char*)d_ws + WGP_OFF + 3 * WMAT_BYTES);

  const int MT64 = (ntok + 63) / 64;   // worst-case 64-row tiles per expert

  route_prep<<<1, 256, 0, stream>>>(route, meta, ntok);
  fill_perm<<<(ntok + 255) / 256, 256, 0, stream>>>(route, meta, perm, ntok);
  x_conv<<<NEXP * MT64, 256, 0, stream>>>(x, meta, perm, xp);
  wgi_conv<<<dim3(8, 16, 16), 256, 0, stream>>>(w_gate, w_in, wgp, wip);
  gemm1<<<NEXP * 16 * MT64, 256, 0, stream>>>(
      xp, wgp, b_gate, wip, b_in, meta, hbuf);
  wo_conv<<<dim3(32, 8, 8), 256, 0, stream>>>(w_out, wop);   // overwrites xp (done)
  gemm2<<<NEXP * 8 * MT64, 512, 0, stream>>>(
      hbuf, wop, b_out, meta, perm, out);
}